// Round 5
// baseline (556.633 us; speedup 1.0000x reference)
//
#include <hip/hip_runtime.h>
#include <math.h>

#define B_   16
#define N_   16384
#define LOGN 14
#define CIN  64
#define COUT 64
#define T_   256
#define M_   2049

__device__ __forceinline__ unsigned br14(unsigned v) {
  return __brev(v) >> 18;   // 14-bit reversal
}

// XOR bank swizzle: bank(n) = (n ^ n>>5 ^ n>>10) & 31. Bijective per 32-block.
__device__ __forceinline__ int SW(int n) {
  return (n & ~31) | ((n ^ (n >> 5) ^ (n >> 10)) & 31);
}

__device__ __forceinline__ void cmul(float ar, float ai, float br, float bi,
                                     float& rr, float& ri) {
  rr = ar * br - ai * bi;
  ri = ar * bi + ai * br;
}

// cos/sin of 2*pi*m/16
__device__ __constant__ float C16[16] = {
  1.f, 0.92387953251f, 0.70710678119f, 0.38268343236f, 0.f, -0.38268343236f,
  -0.70710678119f, -0.92387953251f, -1.f, -0.92387953251f, -0.70710678119f,
  -0.38268343236f, 0.f, 0.38268343236f, 0.70710678119f, 0.92387953251f};
__device__ __constant__ float S16[16] = {
  0.f, 0.38268343236f, 0.70710678119f, 0.92387953251f, 1.f, 0.92387953251f,
  0.70710678119f, 0.38268343236f, 0.f, -0.38268343236f, -0.70710678119f,
  -0.92387953251f, -1.f, -0.92387953251f, -0.70710678119f, -0.38268343236f};

// One radix-16 group = 4 radix-2 DIT substages done in registers.
template <int SIGN, int S0>
__device__ __forceinline__ void group16(float* __restrict__ sre,
                                        float* __restrict__ sim, int tid) {
  const int lo = tid & ((1 << S0) - 1);
  const int hi = tid >> S0;
  const int base = (hi << (S0 + 4)) + lo;
  int pp[16];
  float xr[16], xi[16];
#pragma unroll
  for (int j = 0; j < 16; ++j) {
    pp[j] = SW(base + (j << S0));
    xr[j] = sre[pp[j]];
    xi[j] = sim[pp[j]];
  }
  float th = 6.283185307179586f * (float)lo / (float)(16 << S0);
  float sn, cs;
  __sincosf(th, &sn, &cs);
  float w1r = cs, w1i = (float)SIGN * sn;
  float w2r, w2i, w4r, w4i, w8r, w8i;
  cmul(w1r, w1i, w1r, w1i, w2r, w2i);
  cmul(w2r, w2i, w2r, w2i, w4r, w4i);
  cmul(w4r, w4i, w4r, w4i, w8r, w8i);
  {
#pragma unroll
    for (int j = 0; j < 16; j += 2) {
      float br, bi;
      cmul(xr[j + 1], xi[j + 1], w8r, w8i, br, bi);
      xr[j + 1] = xr[j] - br; xi[j + 1] = xi[j] - bi;
      xr[j] += br; xi[j] += bi;
    }
  }
  {
    float tr[2], ti[2];
    tr[0] = w4r; ti[0] = w4i;
    cmul(w4r, w4i, C16[4], (float)SIGN * S16[4], tr[1], ti[1]);
#pragma unroll
    for (int j = 0; j < 16; ++j) {
      if ((j & 2) == 0) {
        int jl = j & 1;
        float br, bi;
        cmul(xr[j + 2], xi[j + 2], tr[jl], ti[jl], br, bi);
        xr[j + 2] = xr[j] - br; xi[j + 2] = xi[j] - bi;
        xr[j] += br; xi[j] += bi;
      }
    }
  }
  {
    float tr[4], ti[4];
#pragma unroll
    for (int jl = 0; jl < 4; ++jl)
      cmul(w2r, w2i, C16[2 * jl], (float)SIGN * S16[2 * jl], tr[jl], ti[jl]);
#pragma unroll
    for (int j = 0; j < 16; ++j) {
      if ((j & 4) == 0) {
        int jl = j & 3;
        float br, bi;
        cmul(xr[j + 4], xi[j + 4], tr[jl], ti[jl], br, bi);
        xr[j + 4] = xr[j] - br; xi[j + 4] = xi[j] - bi;
        xr[j] += br; xi[j] += bi;
      }
    }
  }
  {
    float tr[8], ti[8];
#pragma unroll
    for (int jl = 0; jl < 8; ++jl)
      cmul(w1r, w1i, C16[jl], (float)SIGN * S16[jl], tr[jl], ti[jl]);
#pragma unroll
    for (int j = 0; j < 8; ++j) {
      float br, bi;
      cmul(xr[j + 8], xi[j + 8], tr[j], ti[j], br, bi);
      xr[j + 8] = xr[j] - br; xi[j + 8] = xi[j] - bi;
      xr[j] += br; xi[j] += bi;
    }
  }
#pragma unroll
  for (int j = 0; j < 16; ++j) {
    sre[pp[j]] = xr[j];
    sim[pp[j]] = xi[j];
  }
}

// Merged radix-4 stage: covers the two radix-2 stages (spans 4096 and 8192)
// in one LDS round-trip. 1024 threads x 4 groups of 4 points.
template <int SIGN>
__device__ __forceinline__ void stage4(float* __restrict__ sre,
                                       float* __restrict__ sim, int tid) {
#pragma unroll
  for (int s = 0; s < 4; ++s) {
    int i = tid + 1024 * s;          // 0..4095
    int p0 = SW(i), p1 = SW(i + 4096), p2 = SW(i + 8192), p3 = SW(i + 12288);
    float a0r = sre[p0], a0i = sim[p0];
    float a1r = sre[p1], a1i = sim[p1];
    float a2r = sre[p2], a2i = sim[p2];
    float a3r = sre[p3], a3i = sim[p3];
    float th = 6.283185307179586f * (float)i / 16384.0f;
    float sn, cs;
    __sincosf(th, &sn, &cs);
    float w1r = cs, w1i = (float)SIGN * sn;        // W_16384^i
    float w2r, w2i;
    cmul(w1r, w1i, w1r, w1i, w2r, w2i);            // W_8192^i
    // span-4096 sub-stage (pairs (i,i+4096) and (i+8192,i+12288), tw = W_8192^i)
    float br, bi;
    cmul(a1r, a1i, w2r, w2i, br, bi);
    float t0r = a0r + br, t0i = a0i + bi;
    float t1r = a0r - br, t1i = a0i - bi;
    cmul(a3r, a3i, w2r, w2i, br, bi);
    float t2r = a2r + br, t2i = a2i + bi;
    float t3r = a2r - br, t3i = a2i - bi;
    // span-8192 sub-stage: (i,i+8192) tw=W^i ; (i+4096,i+12288) tw=W^i*(0,SIGN)
    cmul(t2r, t2i, w1r, w1i, br, bi);
    sre[p0] = t0r + br; sim[p0] = t0i + bi;
    sre[p2] = t0r - br; sim[p2] = t0i - bi;
    float wbr = -(float)SIGN * w1i, wbi = (float)SIGN * w1r;
    cmul(t3r, t3i, wbr, wbi, br, bi);
    sre[p1] = t1r + br; sim[p1] = t1i + bi;
    sre[p3] = t1r - br; sim[p3] = t1i - bi;
  }
}

template <int SIGN>
__device__ __forceinline__ void fft_core(float* __restrict__ sre,
                                         float* __restrict__ sim, int tid) {
  group16<SIGN, 0>(sre, sim, tid); __syncthreads();
  group16<SIGN, 4>(sre, sim, tid); __syncthreads();
  group16<SIGN, 8>(sre, sim, tid); __syncthreads();
  stage4<SIGN>(sre, sim, tid);     __syncthreads();
}

// Block id -> (b, c0): 256 blocks = 16 b x 16 channel-quads. The 4 blocks
// sharing each 64B line (quads t=0..3 of one 16-ch group) get ids t*64+u,
// equal mod 8 -> same XCD under round-robin dispatch; all 256 co-resident.
__device__ __forceinline__ void decode_bc4(int id, int& b, int& c0) {
  int t = id >> 6, u = id & 63;
  b  = u >> 2;
  c0 = (u & 3) * 16 + t * 4;
}

// ---------------- Kernel A: t_mod = t_emb @ dense^T (complex) ----------------
__global__ __launch_bounds__(256) void tmod_kernel(
    const float* __restrict__ t_emb,
    const float* __restrict__ dwr, const float* __restrict__ dwi,
    float* __restrict__ tmr, float* __restrict__ tmi) {
  int wave = threadIdx.x >> 6;
  int lane = threadIdx.x & 63;
  int p = blockIdx.x * 4 + wave;
  if (p >= B_ * M_) return;
  int b = p / M_, i = p % M_;
  float ar = 0.f, ai = 0.f;
  for (int j = 0; j < 4; ++j) {
    int t = lane + 64 * j;
    float te = t_emb[b * T_ + t];
    ar += te * dwr[(size_t)i * T_ + t];
    ai += te * dwi[(size_t)i * T_ + t];
  }
  for (int off = 32; off > 0; off >>= 1) {
    ar += __shfl_down(ar, off, 64);
    ai += __shfl_down(ai, off, 64);
  }
  if (lane == 0) { tmr[b * M_ + i] = ar; tmi[b * M_ + i] = ai; }
}

// rfft split + store for one channel pair (even=o0 plane, odd=o0+M_).
__device__ __forceinline__ void rfft_out(const float* __restrict__ sre,
                                         const float* __restrict__ sim,
                                         float* __restrict__ Xre,
                                         float* __restrict__ Xim,
                                         size_t o0, int tid) {
  const float sc = 1.0f / (float)N_;
  size_t o1 = o0 + M_;
  for (int k = tid; k < M_; k += 1024) {
    int mk = (N_ - k) & (N_ - 1);
    int pk = SW(k), pm = SW(mk);
    float zr = sre[pk], zi = sim[pk];
    float mr = sre[pm], mi = sim[pm];
    float X0r = 0.5f * (zr + mr), X0i = 0.5f * (zi - mi);
    float X1r = 0.5f * (zi + mi), X1i = -0.5f * (zr - mr);
    Xre[o0 + k] = X0r * sc; Xim[o0 + k] = X0i * sc;
    Xre[o1 + k] = X1r * sc; Xim[o1 + k] = X1i * sc;
  }
}

// ------- Kernel B: fused load + two 16384-pt FFTs (4 channels) per block -----
__global__ __launch_bounds__(1024) void fft_fwd_fused(
    const float* __restrict__ x,
    float* __restrict__ Xre, float* __restrict__ Xim) {
  __shared__ float sre[N_], sim[N_];    // 128 KiB
  int b, c0;
  decode_bc4(blockIdx.x, b, c0);
  const int tid = threadIdx.x;
  const float* xb = x + (size_t)b * N_ * CIN + c0;
  float4 v[16];
#pragma unroll
  for (int s = 0; s < 16; ++s) {
    int n = tid + 1024 * s;
    v[s] = *(const float4*)(xb + (size_t)n * CIN);
  }
  float2 z2[16];
#pragma unroll
  for (int s = 0; s < 16; ++s) {
    int n = tid + 1024 * s;
    int rr = SW((int)br14((unsigned)n));
    sre[rr] = v[s].x;
    sim[rr] = v[s].y;
    z2[s] = make_float2(v[s].z, v[s].w);
  }
  __syncthreads();
  fft_core<-1>(sre, sim, tid);
  rfft_out(sre, sim, Xre, Xim, (size_t)(b * CIN + c0) * M_, tid);
  __syncthreads();
#pragma unroll
  for (int s = 0; s < 16; ++s) {
    int n = tid + 1024 * s;
    int rr = SW((int)br14((unsigned)n));
    sre[rr] = z2[s].x;
    sim[rr] = z2[s].y;
  }
  __syncthreads();
  fft_core<-1>(sre, sim, tid);
  rfft_out(sre, sim, Xre, Xim, (size_t)(b * CIN + c0 + 2) * M_, tid);
}

// ---------------- generic 2-plane tiled transpose (R x C -> C x R) ----------
__global__ __launch_bounds__(256) void transpose2(
    const float* __restrict__ s0, const float* __restrict__ s1,
    float* __restrict__ d0, float* __restrict__ d1, int R, int C) {
  __shared__ float tile[32][33];
  const float* src = blockIdx.z ? s1 : s0;
  float* dst = blockIdx.z ? d1 : d0;
  int c0 = blockIdx.x * 32, r0 = blockIdx.y * 32;
  int tx = threadIdx.x & 31, ty = threadIdx.x >> 5;
  for (int p = 0; p < 32; p += 8) {
    int r = r0 + ty + p, c = c0 + tx;
    tile[ty + p][tx] = (r < R && c < C) ? src[(size_t)r * C + c] : 0.f;
  }
  __syncthreads();
  for (int p = 0; p < 32; p += 8) {
    int r = c0 + ty + p, c = r0 + tx;
    if (r < C && c < R) dst[(size_t)r * R + c] = tile[tx][ty + p];
  }
}

// ---------------- Kernel C: per-frequency channel mix via MFMA (bf16x3) ------
typedef short  s8v  __attribute__((ext_vector_type(8)));
typedef float  f4v  __attribute__((ext_vector_type(4)));

__device__ __forceinline__ unsigned short f2bf_hi(float x) {
  unsigned u = __float_as_uint(x);
  unsigned r = (u + 0x7fffu + ((u >> 16) & 1u)) >> 16;   // RNE
  return (unsigned short)r;
}

// B-fragment LDS index: slab = (n>>4)*2 + (k>>5); L = (n&15) + ((k>>3)&3)*16; j = k&7
__device__ __forceinline__ int fbi(int k, int n) {
  return ((((n >> 4) * 2 + (k >> 5)) << 9) | (((n & 15) + (((k >> 3) & 3) << 4)) << 3) | (k & 7));
}
// A-fragment LDS index: slab = k>>5
__device__ __forceinline__ int fai(int k, int m) {
  return (((k >> 5) << 9) | (((m & 15) + (((k >> 3) & 3) << 4)) << 3) | (k & 7));
}

__global__ __launch_bounds__(256) void mix_mfma(
    const float* __restrict__ Xtr, const float* __restrict__ Xti,
    const float* __restrict__ Wr_g, const float* __restrict__ Wi_g,
    const float* __restrict__ tmr, const float* __restrict__ tmi,
    float* __restrict__ Yr_g, float* __restrict__ Yi_g) {
  __shared__ __align__(16) unsigned short BrH[4096], BrL[4096], BiH[4096], BiL[4096];
  __shared__ __align__(16) unsigned short ArH[1024], ArL[1024];
  __shared__ __align__(16) unsigned short AiH[1024], AiL[1024];
  __shared__ __align__(16) unsigned short AnH[1024], AnL[1024];  // -Ai
  __shared__ float tms[32];
  const int i   = blockIdx.x;
  const int tid = threadIdx.x;

  const float4* wr4 = (const float4*)(Wr_g + (size_t)i * 4096);
  const float4* wi4 = (const float4*)(Wi_g + (size_t)i * 4096);
#pragma unroll
  for (int it = 0; it < 4; ++it) {
    int f4 = it * 256 + tid;          // 0..1023
    float4 vr = wr4[f4];
    float4 vi = wi4[f4];
    int idx0 = f4 * 4;
    float er[4] = {vr.x, vr.y, vr.z, vr.w};
    float ei[4] = {vi.x, vi.y, vi.z, vi.w};
#pragma unroll
    for (int e = 0; e < 4; ++e) {
      int idx = idx0 + e;
      int k = idx >> 6, n = idx & 63;
      int a = fbi(k, n);
      unsigned short h = f2bf_hi(er[e]);
      float hf = __uint_as_float(((unsigned)h) << 16);
      BrH[a] = h; BrL[a] = f2bf_hi(er[e] - hf);
      h = f2bf_hi(ei[e]);
      hf = __uint_as_float(((unsigned)h) << 16);
      BiH[a] = h; BiL[a] = f2bf_hi(ei[e] - hf);
    }
  }
  {
    float4 vr = ((const float4*)(Xtr + (size_t)i * 1024))[tid];
    float4 vi = ((const float4*)(Xti + (size_t)i * 1024))[tid];
    float er[4] = {vr.x, vr.y, vr.z, vr.w};
    float ei[4] = {vi.x, vi.y, vi.z, vi.w};
    int idx0 = tid * 4;
#pragma unroll
    for (int e = 0; e < 4; ++e) {
      int idx = idx0 + e;
      int m = idx >> 6, k = idx & 63;
      int a = fai(k, m);
      unsigned short h = f2bf_hi(er[e]);
      float hf = __uint_as_float(((unsigned)h) << 16);
      ArH[a] = h; ArL[a] = f2bf_hi(er[e] - hf);
      h = f2bf_hi(ei[e]);
      hf = __uint_as_float(((unsigned)h) << 16);
      unsigned short l = f2bf_hi(ei[e] - __uint_as_float(((unsigned)h) << 16));
      AiH[a] = h; AiL[a] = l;
      AnH[a] = h ^ 0x8000u; AnL[a] = l ^ 0x8000u;
    }
  }
  if (tid < 16) {
    tms[tid]      = tmr[tid * M_ + i];
    tms[16 + tid] = tmi[tid * M_ + i];
  }
  __syncthreads();

  const int w = tid >> 6, L = tid & 63;
  const s8v* pArH = (const s8v*)ArH; const s8v* pArL = (const s8v*)ArL;
  const s8v* pAiH = (const s8v*)AiH; const s8v* pAiL = (const s8v*)AiL;
  const s8v* pAnH = (const s8v*)AnH; const s8v* pAnL = (const s8v*)AnL;
  const s8v* pBrH = (const s8v*)BrH; const s8v* pBrL = (const s8v*)BrL;
  const s8v* pBiH = (const s8v*)BiH; const s8v* pBiL = (const s8v*)BiL;

  f4v cr = {0.f, 0.f, 0.f, 0.f}, ci = {0.f, 0.f, 0.f, 0.f};
#pragma unroll
  for (int s = 0; s < 2; ++s) {
    s8v arh = pArH[s * 64 + L], arl = pArL[s * 64 + L];
    s8v aih = pAiH[s * 64 + L], ail = pAiL[s * 64 + L];
    s8v anh = pAnH[s * 64 + L], anl = pAnL[s * 64 + L];
    int bo = (w * 2 + s) * 64 + L;
    s8v brh = pBrH[bo], brl = pBrL[bo];
    s8v bih = pBiH[bo], bil = pBiL[bo];
    cr = __builtin_amdgcn_mfma_f32_16x16x32_bf16(arh, brh, cr, 0, 0, 0);
    cr = __builtin_amdgcn_mfma_f32_16x16x32_bf16(arh, brl, cr, 0, 0, 0);
    cr = __builtin_amdgcn_mfma_f32_16x16x32_bf16(arl, brh, cr, 0, 0, 0);
    cr = __builtin_amdgcn_mfma_f32_16x16x32_bf16(anh, bih, cr, 0, 0, 0);
    cr = __builtin_amdgcn_mfma_f32_16x16x32_bf16(anh, bil, cr, 0, 0, 0);
    cr = __builtin_amdgcn_mfma_f32_16x16x32_bf16(anl, bih, cr, 0, 0, 0);
    ci = __builtin_amdgcn_mfma_f32_16x16x32_bf16(arh, bih, ci, 0, 0, 0);
    ci = __builtin_amdgcn_mfma_f32_16x16x32_bf16(arh, bil, ci, 0, 0, 0);
    ci = __builtin_amdgcn_mfma_f32_16x16x32_bf16(arl, bih, ci, 0, 0, 0);
    ci = __builtin_amdgcn_mfma_f32_16x16x32_bf16(aih, brh, ci, 0, 0, 0);
    ci = __builtin_amdgcn_mfma_f32_16x16x32_bf16(aih, brl, ci, 0, 0, 0);
    ci = __builtin_amdgcn_mfma_f32_16x16x32_bf16(ail, brh, ci, 0, 0, 0);
  }

  const int n = (L & 15) + 16 * w;
  const int quad = L >> 4;
#pragma unroll
  for (int r = 0; r < 4; ++r) {
    int m = quad * 4 + r;
    float tr = tms[m], ti = tms[16 + m];
    float yr = tr * cr[r] - ti * ci[r];
    float yi = tr * ci[r] + ti * cr[r];
    size_t o = (size_t)i * 1024 + m * 64 + n;
    Yr_g[o] = yr;
    Yi_g[o] = yi;
  }
}

// Hermitian assemble of Z = Y0ext + i*Y1ext for one channel pair into LDS.
__device__ __forceinline__ void herm_load(const float* __restrict__ Ytr,
                                          const float* __restrict__ Yti,
                                          size_t y0, float* __restrict__ sre,
                                          float* __restrict__ sim, int tid) {
  size_t y1 = y0 + M_;
#pragma unroll
  for (int s = 0; s < 16; ++s) {
    int k = tid + 1024 * s;
    float Zr = 0.f, Zi = 0.f;
    if (k < M_) {
      float a0r = Ytr[y0 + k], a0i = Yti[y0 + k];
      float a1r = Ytr[y1 + k], a1i = Yti[y1 + k];
      Zr = a0r - a1i;                 // Y0[k] + i*Y1[k]
      Zi = a0i + a1r;
    }
    int m = N_ - k;
    if (k > 0 && m < M_) {
      float b0r = Ytr[y0 + m], b0i = Yti[y0 + m];
      float b1r = Ytr[y1 + m], b1i = Yti[y1 + m];
      Zr += b0r + b1i;                // conj(Y0[m]) + i*conj(Y1[m])
      Zi += b1r - b0i;
    }
    int rr = SW((int)br14((unsigned)k));
    sre[rr] = Zr;
    sim[rr] = Zi;
  }
}

// ------- Kernel D: fused hermitian assemble + two inverse FFTs + store -------
__global__ __launch_bounds__(1024) void fft_inv_fused(
    const float* __restrict__ Ytr, const float* __restrict__ Yti,
    float* __restrict__ out) {
  __shared__ float sre[N_], sim[N_];    // 128 KiB
  int b, c0;
  decode_bc4(blockIdx.x, b, c0);
  const int tid = threadIdx.x;
  herm_load(Ytr, Yti, (size_t)(b * COUT + c0) * M_, sre, sim, tid);
  __syncthreads();
  fft_core<1>(sre, sim, tid);
  float2 o1[16];
#pragma unroll
  for (int s = 0; s < 16; ++s) {
    int p = SW(tid + 1024 * s);
    o1[s] = make_float2(sre[p], sim[p]);
  }
  __syncthreads();
  herm_load(Ytr, Yti, (size_t)(b * COUT + c0 + 2) * M_, sre, sim, tid);
  __syncthreads();
  fft_core<1>(sre, sim, tid);
  float* ob = out + (size_t)b * N_ * COUT + c0;
#pragma unroll
  for (int s = 0; s < 16; ++s) {
    int n = tid + 1024 * s;
    int p = SW(n);
    *(float4*)(ob + (size_t)n * COUT) =
        make_float4(o1[s].x, o1[s].y, sre[p], sim[p]);
  }
}

extern "C" void kernel_launch(void* const* d_in, const int* in_sizes, int n_in,
                              void* d_out, int out_size, void* d_ws, size_t ws_size,
                              hipStream_t stream) {
  const float* x    = (const float*)d_in[0];
  const float* temb = (const float*)d_in[1];
  const float* wr   = (const float*)d_in[2];
  const float* wi   = (const float*)d_in[3];
  const float* dwr  = (const float*)d_in[4];
  const float* dwi  = (const float*)d_in[5];
  float* out = (float*)d_out;

  float* ws  = (float*)d_ws;
  float* tmr = ws;
  float* tmi = tmr + 32784;
  float* Xre = tmi + 32784;                // X (b,c,k) — later Yt (b,o,k)
  float* Xim = Xre + 2098176;
  float* Xtr = Xim + 2098176;              // Xt (k,b,c) — later Y (i,b,o)
  float* Xti = Xtr + 2098176;

  tmod_kernel<<<dim3((B_ * M_ + 3) / 4), 256, 0, stream>>>(temb, dwr, dwi, tmr, tmi);
  fft_fwd_fused<<<dim3(B_ * CIN / 4), 1024, 0, stream>>>(x, Xre, Xim);
  transpose2<<<dim3((M_ + 31) / 32, (B_ * CIN + 31) / 32, 2), 256, 0, stream>>>(
      Xre, Xim, Xtr, Xti, B_ * CIN, M_);
  mix_mfma<<<dim3(M_), 256, 0, stream>>>(Xtr, Xti, wr, wi, tmr, tmi, Xtr, Xti);
  transpose2<<<dim3((B_ * COUT + 31) / 32, (M_ + 31) / 32, 2), 256, 0, stream>>>(
      Xtr, Xti, Xre, Xim, M_, B_ * COUT);
  fft_inv_fused<<<dim3(B_ * COUT / 4), 1024, 0, stream>>>(Xre, Xim, out);
}

// Round 6
// 313.496 us; speedup vs baseline: 1.7756x; 1.7756x over previous
//
#include <hip/hip_runtime.h>
#include <math.h>

#define B_   16
#define N_   16384
#define H_   8192      // N/2
#define LOGH 13
#define CIN  64
#define COUT 64
#define T_   256
#define M_   2049

__device__ __forceinline__ unsigned br13(unsigned v) {
  return __brev(v) >> 19;   // 13-bit reversal
}

// XOR bank swizzle: bank(n) = (n ^ n>>5 ^ n>>10) & 31. Bijective per 32-block.
__device__ __forceinline__ int SW(int n) {
  return (n & ~31) | ((n ^ (n >> 5) ^ (n >> 10)) & 31);
}

__device__ __forceinline__ void cmul(float ar, float ai, float br, float bi,
                                     float& rr, float& ri) {
  rr = ar * br - ai * bi;
  ri = ar * bi + ai * br;
}

// cos/sin of 2*pi*m/16
__device__ __constant__ float C16[16] = {
  1.f, 0.92387953251f, 0.70710678119f, 0.38268343236f, 0.f, -0.38268343236f,
  -0.70710678119f, -0.92387953251f, -1.f, -0.92387953251f, -0.70710678119f,
  -0.38268343236f, 0.f, 0.38268343236f, 0.70710678119f, 0.92387953251f};
__device__ __constant__ float S16[16] = {
  0.f, 0.38268343236f, 0.70710678119f, 0.92387953251f, 1.f, 0.92387953251f,
  0.70710678119f, 0.38268343236f, 0.f, -0.38268343236f, -0.70710678119f,
  -0.92387953251f, -1.f, -0.92387953251f, -0.70710678119f, -0.38268343236f};

// One radix-16 group = 4 radix-2 DIT substages done in registers.
template <int SIGN, int S0>
__device__ __forceinline__ void group16(float* __restrict__ sre,
                                        float* __restrict__ sim, int tid) {
  const int lo = tid & ((1 << S0) - 1);
  const int hi = tid >> S0;
  const int base = (hi << (S0 + 4)) + lo;
  int pp[16];
  float xr[16], xi[16];
#pragma unroll
  for (int j = 0; j < 16; ++j) {
    pp[j] = SW(base + (j << S0));
    xr[j] = sre[pp[j]];
    xi[j] = sim[pp[j]];
  }
  float th = 6.283185307179586f * (float)lo / (float)(16 << S0);
  float sn, cs;
  __sincosf(th, &sn, &cs);
  float w1r = cs, w1i = (float)SIGN * sn;
  float w2r, w2i, w4r, w4i, w8r, w8i;
  cmul(w1r, w1i, w1r, w1i, w2r, w2i);
  cmul(w2r, w2i, w2r, w2i, w4r, w4i);
  cmul(w4r, w4i, w4r, w4i, w8r, w8i);
  {
#pragma unroll
    for (int j = 0; j < 16; j += 2) {
      float br, bi;
      cmul(xr[j + 1], xi[j + 1], w8r, w8i, br, bi);
      xr[j + 1] = xr[j] - br; xi[j + 1] = xi[j] - bi;
      xr[j] += br; xi[j] += bi;
    }
  }
  {
    float tr[2], ti[2];
    tr[0] = w4r; ti[0] = w4i;
    cmul(w4r, w4i, C16[4], (float)SIGN * S16[4], tr[1], ti[1]);
#pragma unroll
    for (int j = 0; j < 16; ++j) {
      if ((j & 2) == 0) {
        int jl = j & 1;
        float br, bi;
        cmul(xr[j + 2], xi[j + 2], tr[jl], ti[jl], br, bi);
        xr[j + 2] = xr[j] - br; xi[j + 2] = xi[j] - bi;
        xr[j] += br; xi[j] += bi;
      }
    }
  }
  {
    float tr[4], ti[4];
#pragma unroll
    for (int jl = 0; jl < 4; ++jl)
      cmul(w2r, w2i, C16[2 * jl], (float)SIGN * S16[2 * jl], tr[jl], ti[jl]);
#pragma unroll
    for (int j = 0; j < 16; ++j) {
      if ((j & 4) == 0) {
        int jl = j & 3;
        float br, bi;
        cmul(xr[j + 4], xi[j + 4], tr[jl], ti[jl], br, bi);
        xr[j + 4] = xr[j] - br; xi[j + 4] = xi[j] - bi;
        xr[j] += br; xi[j] += bi;
      }
    }
  }
  {
    float tr[8], ti[8];
#pragma unroll
    for (int jl = 0; jl < 8; ++jl)
      cmul(w1r, w1i, C16[jl], (float)SIGN * S16[jl], tr[jl], ti[jl]);
#pragma unroll
    for (int j = 0; j < 8; ++j) {
      float br, bi;
      cmul(xr[j + 8], xi[j + 8], tr[j], ti[j], br, bi);
      xr[j + 8] = xr[j] - br; xi[j + 8] = xi[j] - bi;
      xr[j] += br; xi[j] += bi;
    }
  }
#pragma unroll
  for (int j = 0; j < 16; ++j) {
    sre[pp[j]] = xr[j];
    sim[pp[j]] = xi[j];
  }
}

// Final radix-2 stage (lh=12): pairs (n, n+4096).
template <int SIGN>
__device__ __forceinline__ void stageD(float* __restrict__ sre,
                                       float* __restrict__ sim, int tid) {
  float th = 6.283185307179586f * (float)tid / 8192.0f;
  float sn, cs;
  __sincosf(th, &sn, &cs);
  float wtr = cs, wti = (float)SIGN * sn;
#pragma unroll
  for (int s = 0; s < 8; ++s) {
    float twr, twi;
    cmul(wtr, wti, C16[s], (float)SIGN * S16[s], twr, twi);
    int i0 = tid + 512 * s;
    int p0 = SW(i0), p1 = SW(i0 + 4096);
    float br, bi;
    cmul(sre[p1], sim[p1], twr, twi, br, bi);
    float ar = sre[p0], ai = sim[p0];
    sre[p0] = ar + br; sim[p0] = ai + bi;
    sre[p1] = ar - br; sim[p1] = ai - bi;
  }
}

// ---------------- Kernel A: t_mod = t_emb @ dense^T (complex) ----------------
__global__ __launch_bounds__(256) void tmod_kernel(
    const float* __restrict__ t_emb,
    const float* __restrict__ dwr, const float* __restrict__ dwi,
    float* __restrict__ tmr, float* __restrict__ tmi) {
  int wave = threadIdx.x >> 6;
  int lane = threadIdx.x & 63;
  int p = blockIdx.x * 4 + wave;
  if (p >= B_ * M_) return;
  int b = p / M_, i = p % M_;
  float ar = 0.f, ai = 0.f;
  for (int j = 0; j < 4; ++j) {
    int t = lane + 64 * j;
    float te = t_emb[b * T_ + t];
    ar += te * dwr[(size_t)i * T_ + t];
    ai += te * dwi[(size_t)i * T_ + t];
  }
  for (int off = 32; off > 0; off >>= 1) {
    ar += __shfl_down(ar, off, 64);
    ai += __shfl_down(ai, off, 64);
  }
  if (lane == 0) { tmr[b * M_ + i] = ar; tmi[b * M_ + i] = ai; }
}

// ------- Kernel T1: x (B,N,C) -> packed complex planes z (B*C, H) ------------
__global__ __launch_bounds__(256) void pack_transpose(
    const float* __restrict__ x, float* __restrict__ zre, float* __restrict__ zim) {
  __shared__ float tile[64][65];
  int b = blockIdx.y, nt = blockIdx.x;
  int n0 = nt * 64;
  int j  = threadIdx.x & 63;
  int iy = threadIdx.x >> 6;
  for (int p = 0; p < 16; ++p) {
    int i = iy + 4 * p;
    tile[i][j] = x[((size_t)(b * N_ + n0 + i)) * CIN + j];
  }
  __syncthreads();
  int ii = threadIdx.x & 31;
  int cy = threadIdx.x >> 5;
  int h0 = nt * 32;
  for (int p = 0; p < 8; ++p) {
    int c = cy + 8 * p;
    size_t o = (size_t)(b * CIN + c) * H_ + h0 + ii;
    zre[o] = tile[2 * ii][c];
    zim[o] = tile[2 * ii + 1][c];
  }
}

// ---------------- Kernel B: forward FFT (length H) + rfft split --------------
__global__ __launch_bounds__(512, 4) void fft_fwd(
    const float* __restrict__ zre, const float* __restrict__ zim,
    float* __restrict__ Xre, float* __restrict__ Xim) {
  __shared__ float sre[H_], sim[H_];
  int bc = blockIdx.x;
  int tid = threadIdx.x;
  size_t base = (size_t)bc * H_;
#pragma unroll
  for (int s = 0; s < 16; ++s) {
    int n = tid + 512 * s;
    int r = SW((int)br13(n));
    sre[r] = zre[base + n];
    sim[r] = zim[base + n];
  }
  __syncthreads();
  group16<-1, 0>(sre, sim, tid); __syncthreads();
  group16<-1, 4>(sre, sim, tid); __syncthreads();
  group16<-1, 8>(sre, sim, tid); __syncthreads();
  stageD<-1>(sre, sim, tid);     __syncthreads();
  const float sc = 1.0f / (float)N_;
  for (int k = tid; k < M_; k += 512) {
    int mk = (H_ - k) & (H_ - 1);
    int pk = SW(k), pm = SW(mk);
    float zr = sre[pk], zi = sim[pk];
    float mr = sre[pm], mi = -sim[pm];
    float Er = 0.5f * (zr + mr), Ei = 0.5f * (zi + mi);
    float Dr = zr - mr,          Di = zi - mi;
    float Or = 0.5f * Di,        Oi = -0.5f * Dr;
    float ang = -6.283185307179586f * (float)k / (float)N_;
    float sn, cs;
    __sincosf(ang, &sn, &cs);
    float Xr = Er + cs * Or - sn * Oi;
    float Xi = Ei + cs * Oi + sn * Or;
    Xre[(size_t)bc * M_ + k] = Xr * sc;
    Xim[(size_t)bc * M_ + k] = Xi * sc;
  }
}

// ---------------- Kernel C: per-frequency channel mix via MFMA (bf16x3) ------
// Y[i,b,o] = tmod[b,i] * sum_c X[i,b,c]*W[i,c,o]
// A-read: directly from X (bc, M) layout at stride M (scattered dword reads;
// dedup'd by L2/L3, zero HBM amplification — reads tolerate scatter).
// Y-write: coalesced (i, bo) rows — writes must stay line-coalesced.
typedef short  s8v  __attribute__((ext_vector_type(8)));
typedef float  f4v  __attribute__((ext_vector_type(4)));

__device__ __forceinline__ unsigned short f2bf_hi(float x) {
  unsigned u = __float_as_uint(x);
  unsigned r = (u + 0x7fffu + ((u >> 16) & 1u)) >> 16;   // RNE
  return (unsigned short)r;
}

// B-fragment LDS index: slab = (n>>4)*2 + (k>>5); L = (n&15) + ((k>>3)&3)*16; j = k&7
__device__ __forceinline__ int fbi(int k, int n) {
  return ((((n >> 4) * 2 + (k >> 5)) << 9) | (((n & 15) + (((k >> 3) & 3) << 4)) << 3) | (k & 7));
}
// A-fragment LDS index: slab = k>>5
__device__ __forceinline__ int fai(int k, int m) {
  return (((k >> 5) << 9) | (((m & 15) + (((k >> 3) & 3) << 4)) << 3) | (k & 7));
}

__global__ __launch_bounds__(256) void mix_mfma(
    const float* __restrict__ Xre, const float* __restrict__ Xim,
    const float* __restrict__ Wr_g, const float* __restrict__ Wi_g,
    const float* __restrict__ tmr, const float* __restrict__ tmi,
    float* __restrict__ Yr_g, float* __restrict__ Yi_g) {
  __shared__ __align__(16) unsigned short BrH[4096], BrL[4096], BiH[4096], BiL[4096];
  __shared__ __align__(16) unsigned short ArH[1024], ArL[1024];
  __shared__ __align__(16) unsigned short AiH[1024], AiL[1024];
  __shared__ __align__(16) unsigned short AnH[1024], AnL[1024];  // -Ai
  __shared__ float tms[32];
  const int i   = blockIdx.x;
  const int tid = threadIdx.x;

  // --- stage X -> bf16 hi/lo A-fragments (+negated imag); strided reads ---
  {
    int idx0 = tid * 4;
    float er[4], ei[4];
#pragma unroll
    for (int e = 0; e < 4; ++e) {
      int idx = idx0 + e;                       // bc = b*64 + c, 0..1023
      er[e] = Xre[(size_t)idx * M_ + i];
      ei[e] = Xim[(size_t)idx * M_ + i];
    }
#pragma unroll
    for (int e = 0; e < 4; ++e) {
      int idx = idx0 + e;
      int m = idx >> 6, k = idx & 63;
      int a = fai(k, m);
      unsigned short h = f2bf_hi(er[e]);
      float hf = __uint_as_float(((unsigned)h) << 16);
      ArH[a] = h; ArL[a] = f2bf_hi(er[e] - hf);
      h = f2bf_hi(ei[e]);
      unsigned short l = f2bf_hi(ei[e] - __uint_as_float(((unsigned)h) << 16));
      AiH[a] = h; AiL[a] = l;
      AnH[a] = h ^ 0x8000u; AnL[a] = l ^ 0x8000u;
    }
  }
  // --- stage W -> bf16 hi/lo fragments ---
  const float4* wr4 = (const float4*)(Wr_g + (size_t)i * 4096);
  const float4* wi4 = (const float4*)(Wi_g + (size_t)i * 4096);
#pragma unroll
  for (int it = 0; it < 4; ++it) {
    int f4 = it * 256 + tid;          // 0..1023
    float4 vr = wr4[f4];
    float4 vi = wi4[f4];
    int idx0 = f4 * 4;
    float er[4] = {vr.x, vr.y, vr.z, vr.w};
    float ei[4] = {vi.x, vi.y, vi.z, vi.w};
#pragma unroll
    for (int e = 0; e < 4; ++e) {
      int idx = idx0 + e;
      int k = idx >> 6, n = idx & 63;
      int a = fbi(k, n);
      unsigned short h = f2bf_hi(er[e]);
      float hf = __uint_as_float(((unsigned)h) << 16);
      BrH[a] = h; BrL[a] = f2bf_hi(er[e] - hf);
      h = f2bf_hi(ei[e]);
      hf = __uint_as_float(((unsigned)h) << 16);
      BiH[a] = h; BiL[a] = f2bf_hi(ei[e] - hf);
    }
  }
  if (tid < 16) {
    tms[tid]      = tmr[tid * M_ + i];
    tms[16 + tid] = tmi[tid * M_ + i];
  }
  __syncthreads();

  const int w = tid >> 6, L = tid & 63;
  const s8v* pArH = (const s8v*)ArH; const s8v* pArL = (const s8v*)ArL;
  const s8v* pAiH = (const s8v*)AiH; const s8v* pAiL = (const s8v*)AiL;
  const s8v* pAnH = (const s8v*)AnH; const s8v* pAnL = (const s8v*)AnL;
  const s8v* pBrH = (const s8v*)BrH; const s8v* pBrL = (const s8v*)BrL;
  const s8v* pBiH = (const s8v*)BiH; const s8v* pBiL = (const s8v*)BiL;

  f4v cr = {0.f, 0.f, 0.f, 0.f}, ci = {0.f, 0.f, 0.f, 0.f};
#pragma unroll
  for (int s = 0; s < 2; ++s) {
    s8v arh = pArH[s * 64 + L], arl = pArL[s * 64 + L];
    s8v aih = pAiH[s * 64 + L], ail = pAiL[s * 64 + L];
    s8v anh = pAnH[s * 64 + L], anl = pAnL[s * 64 + L];
    int bo = (w * 2 + s) * 64 + L;
    s8v brh = pBrH[bo], brl = pBrL[bo];
    s8v bih = pBiH[bo], bil = pBiL[bo];
    cr = __builtin_amdgcn_mfma_f32_16x16x32_bf16(arh, brh, cr, 0, 0, 0);
    cr = __builtin_amdgcn_mfma_f32_16x16x32_bf16(arh, brl, cr, 0, 0, 0);
    cr = __builtin_amdgcn_mfma_f32_16x16x32_bf16(arl, brh, cr, 0, 0, 0);
    cr = __builtin_amdgcn_mfma_f32_16x16x32_bf16(anh, bih, cr, 0, 0, 0);
    cr = __builtin_amdgcn_mfma_f32_16x16x32_bf16(anh, bil, cr, 0, 0, 0);
    cr = __builtin_amdgcn_mfma_f32_16x16x32_bf16(anl, bih, cr, 0, 0, 0);
    ci = __builtin_amdgcn_mfma_f32_16x16x32_bf16(arh, bih, ci, 0, 0, 0);
    ci = __builtin_amdgcn_mfma_f32_16x16x32_bf16(arh, bil, ci, 0, 0, 0);
    ci = __builtin_amdgcn_mfma_f32_16x16x32_bf16(arl, bih, ci, 0, 0, 0);
    ci = __builtin_amdgcn_mfma_f32_16x16x32_bf16(aih, brh, ci, 0, 0, 0);
    ci = __builtin_amdgcn_mfma_f32_16x16x32_bf16(aih, brl, ci, 0, 0, 0);
    ci = __builtin_amdgcn_mfma_f32_16x16x32_bf16(ail, brh, ci, 0, 0, 0);
  }

  const int n = (L & 15) + 16 * w;
  const int quad = L >> 4;
#pragma unroll
  for (int r = 0; r < 4; ++r) {
    int m = quad * 4 + r;
    float tr = tms[m], ti = tms[16 + m];
    float yr = tr * cr[r] - ti * ci[r];
    float yi = tr * ci[r] + ti * cr[r];
    size_t o = (size_t)i * 1024 + m * 64 + n;
    Yr_g[o] = yr;
    Yi_g[o] = yi;
  }
}

// ---------------- Kernel D: inverse packing + inverse FFT --------------------
// Reads Y in (k, bo) layout (stride-4KB scattered dwords, L2/L3 dedup'd);
// writes z planes coalesced.
__global__ __launch_bounds__(512, 4) void fft_inv(
    const float* __restrict__ Ytr, const float* __restrict__ Yti,
    float* __restrict__ zre, float* __restrict__ zim) {
  __shared__ float sre[H_], sim[H_];
  int bo = blockIdx.x;
  int tid = threadIdx.x;
#pragma unroll
  for (int s = 0; s < 16; ++s) {
    int k = tid + 512 * s;
    float ykr = 0.f, yki = 0.f, ymr = 0.f, ymi = 0.f;
    if (k < M_) {
      ykr = Ytr[(size_t)k * 1024 + bo];
      yki = Yti[(size_t)k * 1024 + bo];
    }
    int m = H_ - k;
    if (m < M_) {
      ymr = Ytr[(size_t)m * 1024 + bo];
      ymi = -Yti[(size_t)m * 1024 + bo];
    }
    float Sr = ykr + ymr, Si = yki + ymi;
    float Dr = ykr - ymr, Di = yki - ymi;
    float ang = 6.283185307179586f * (float)k / (float)N_;
    float sn, cs;
    __sincosf(ang, &sn, &cs);
    float Zr = Sr - (cs * Di + sn * Dr);
    float Zi = Si + (cs * Dr - sn * Di);
    int r = SW((int)br13(k));
    sre[r] = Zr; sim[r] = Zi;
  }
  __syncthreads();
  group16<1, 0>(sre, sim, tid); __syncthreads();
  group16<1, 4>(sre, sim, tid); __syncthreads();
  group16<1, 8>(sre, sim, tid); __syncthreads();
  stageD<1>(sre, sim, tid);     __syncthreads();
  size_t base = (size_t)bo * H_;
#pragma unroll
  for (int s = 0; s < 16; ++s) {
    int n = tid + 512 * s;
    int p = SW(n);
    zre[base + n] = sre[p];
    zim[base + n] = sim[p];
  }
}

// ------- Kernel T4: z planes (B*Cout, H) -> out (B, N, Cout) -----------------
__global__ __launch_bounds__(256) void unpack_transpose(
    const float* __restrict__ zre, const float* __restrict__ zim,
    float* __restrict__ out) {
  __shared__ float tre[64][33], tim[64][33];
  int b = blockIdx.y, ht = blockIdx.x;
  int h0 = ht * 32;
  int ii = threadIdx.x & 31, cy = threadIdx.x >> 5;
  for (int p = 0; p < 8; ++p) {
    int c = cy + 8 * p;
    size_t idx = (size_t)(b * COUT + c) * H_ + h0 + ii;
    tre[c][ii] = zre[idx];
    tim[c][ii] = zim[idx];
  }
  __syncthreads();
  int o = threadIdx.x & 63, ry = threadIdx.x >> 6;
  for (int p = 0; p < 16; ++p) {
    int r = ry + 4 * p;
    int n = h0 * 2 + r;
    float v = (r & 1) ? tim[o][r >> 1] : tre[o][r >> 1];
    out[((size_t)(b * N_ + n)) * COUT + o] = v;
  }
}

extern "C" void kernel_launch(void* const* d_in, const int* in_sizes, int n_in,
                              void* d_out, int out_size, void* d_ws, size_t ws_size,
                              hipStream_t stream) {
  const float* x    = (const float*)d_in[0];
  const float* temb = (const float*)d_in[1];
  const float* wr   = (const float*)d_in[2];
  const float* wi   = (const float*)d_in[3];
  const float* dwr  = (const float*)d_in[4];
  const float* dwi  = (const float*)d_in[5];
  float* out = (float*)d_out;

  float* ws  = (float*)d_ws;
  float* tmr = ws;
  float* tmi = tmr + 32784;
  float* zre = tmi + 32784;                // (B*C, H) — reused by inverse
  float* zim = zre + 8388608;
  float* Xre = zim + 8388608;              // X (bc, k)
  float* Xim = Xre + 2098176;
  float* Yre = Xim + 2098176;              // Y (k, bo)
  float* Yim = Yre + 2098176;

  tmod_kernel<<<dim3((B_ * M_ + 3) / 4), 256, 0, stream>>>(temb, dwr, dwi, tmr, tmi);
  pack_transpose<<<dim3(N_ / 64, B_), 256, 0, stream>>>(x, zre, zim);
  fft_fwd<<<dim3(B_ * CIN), 512, 0, stream>>>(zre, zim, Xre, Xim);
  mix_mfma<<<dim3(M_), 256, 0, stream>>>(Xre, Xim, wr, wi, tmr, tmi, Yre, Yim);
  fft_inv<<<dim3(B_ * COUT), 512, 0, stream>>>(Yre, Yim, zre, zim);
  unpack_transpose<<<dim3(H_ / 32, B_), 256, 0, stream>>>(zre, zim, out);
}

// Round 7
// 302.892 us; speedup vs baseline: 1.8377x; 1.0350x over previous
//
#include <hip/hip_runtime.h>
#include <math.h>

#define B_   16
#define N_   16384
#define H_   8192      // N/2
#define LOGH 13
#define CIN  64
#define COUT 64
#define T_   256
#define M_   2049

__device__ __forceinline__ unsigned br13(unsigned v) {
  return __brev(v) >> 19;   // 13-bit reversal
}

// XOR bank swizzle: bank(n) = (n ^ n>>5 ^ n>>10) & 31. Bijective per 32-block.
__device__ __forceinline__ int SW(int n) {
  return (n & ~31) | ((n ^ (n >> 5) ^ (n >> 10)) & 31);
}

__device__ __forceinline__ void cmul(float ar, float ai, float br, float bi,
                                     float& rr, float& ri) {
  rr = ar * br - ai * bi;
  ri = ar * bi + ai * br;
}

// cos/sin of 2*pi*m/16
__device__ __constant__ float C16[16] = {
  1.f, 0.92387953251f, 0.70710678119f, 0.38268343236f, 0.f, -0.38268343236f,
  -0.70710678119f, -0.92387953251f, -1.f, -0.92387953251f, -0.70710678119f,
  -0.38268343236f, 0.f, 0.38268343236f, 0.70710678119f, 0.92387953251f};
__device__ __constant__ float S16[16] = {
  0.f, 0.38268343236f, 0.70710678119f, 0.92387953251f, 1.f, 0.92387953251f,
  0.70710678119f, 0.38268343236f, 0.f, -0.38268343236f, -0.70710678119f,
  -0.92387953251f, -1.f, -0.92387953251f, -0.70710678119f, -0.38268343236f};

// One radix-16 group = 4 radix-2 DIT substages done in registers.
template <int SIGN, int S0>
__device__ __forceinline__ void group16(float* __restrict__ sre,
                                        float* __restrict__ sim, int tid) {
  const int lo = tid & ((1 << S0) - 1);
  const int hi = tid >> S0;
  const int base = (hi << (S0 + 4)) + lo;
  int pp[16];
  float xr[16], xi[16];
#pragma unroll
  for (int j = 0; j < 16; ++j) {
    pp[j] = SW(base + (j << S0));
    xr[j] = sre[pp[j]];
    xi[j] = sim[pp[j]];
  }
  float th = 6.283185307179586f * (float)lo / (float)(16 << S0);
  float sn, cs;
  __sincosf(th, &sn, &cs);
  float w1r = cs, w1i = (float)SIGN * sn;
  float w2r, w2i, w4r, w4i, w8r, w8i;
  cmul(w1r, w1i, w1r, w1i, w2r, w2i);
  cmul(w2r, w2i, w2r, w2i, w4r, w4i);
  cmul(w4r, w4i, w4r, w4i, w8r, w8i);
  {
#pragma unroll
    for (int j = 0; j < 16; j += 2) {
      float br, bi;
      cmul(xr[j + 1], xi[j + 1], w8r, w8i, br, bi);
      xr[j + 1] = xr[j] - br; xi[j + 1] = xi[j] - bi;
      xr[j] += br; xi[j] += bi;
    }
  }
  {
    float tr[2], ti[2];
    tr[0] = w4r; ti[0] = w4i;
    cmul(w4r, w4i, C16[4], (float)SIGN * S16[4], tr[1], ti[1]);
#pragma unroll
    for (int j = 0; j < 16; ++j) {
      if ((j & 2) == 0) {
        int jl = j & 1;
        float br, bi;
        cmul(xr[j + 2], xi[j + 2], tr[jl], ti[jl], br, bi);
        xr[j + 2] = xr[j] - br; xi[j + 2] = xi[j] - bi;
        xr[j] += br; xi[j] += bi;
      }
    }
  }
  {
    float tr[4], ti[4];
#pragma unroll
    for (int jl = 0; jl < 4; ++jl)
      cmul(w2r, w2i, C16[2 * jl], (float)SIGN * S16[2 * jl], tr[jl], ti[jl]);
#pragma unroll
    for (int j = 0; j < 16; ++j) {
      if ((j & 4) == 0) {
        int jl = j & 3;
        float br, bi;
        cmul(xr[j + 4], xi[j + 4], tr[jl], ti[jl], br, bi);
        xr[j + 4] = xr[j] - br; xi[j + 4] = xi[j] - bi;
        xr[j] += br; xi[j] += bi;
      }
    }
  }
  {
    float tr[8], ti[8];
#pragma unroll
    for (int jl = 0; jl < 8; ++jl)
      cmul(w1r, w1i, C16[jl], (float)SIGN * S16[jl], tr[jl], ti[jl]);
#pragma unroll
    for (int j = 0; j < 8; ++j) {
      float br, bi;
      cmul(xr[j + 8], xi[j + 8], tr[j], ti[j], br, bi);
      xr[j + 8] = xr[j] - br; xi[j + 8] = xi[j] - bi;
      xr[j] += br; xi[j] += bi;
    }
  }
#pragma unroll
  for (int j = 0; j < 16; ++j) {
    sre[pp[j]] = xr[j];
    sim[pp[j]] = xi[j];
  }
}

// Final radix-2 stage (lh=12): pairs (n, n+4096).
template <int SIGN>
__device__ __forceinline__ void stageD(float* __restrict__ sre,
                                       float* __restrict__ sim, int tid) {
  float th = 6.283185307179586f * (float)tid / 8192.0f;
  float sn, cs;
  __sincosf(th, &sn, &cs);
  float wtr = cs, wti = (float)SIGN * sn;
#pragma unroll
  for (int s = 0; s < 8; ++s) {
    float twr, twi;
    cmul(wtr, wti, C16[s], (float)SIGN * S16[s], twr, twi);
    int i0 = tid + 512 * s;
    int p0 = SW(i0), p1 = SW(i0 + 4096);
    float br, bi;
    cmul(sre[p1], sim[p1], twr, twi, br, bi);
    float ar = sre[p0], ai = sim[p0];
    sre[p0] = ar + br; sim[p0] = ai + bi;
    sre[p1] = ar - br; sim[p1] = ai - bi;
  }
}

// ---------------- Kernel A: t_mod = t_emb @ dense^T (complex) ----------------
__global__ __launch_bounds__(256) void tmod_kernel(
    const float* __restrict__ t_emb,
    const float* __restrict__ dwr, const float* __restrict__ dwi,
    float* __restrict__ tmr, float* __restrict__ tmi) {
  int wave = threadIdx.x >> 6;
  int lane = threadIdx.x & 63;
  int p = blockIdx.x * 4 + wave;
  if (p >= B_ * M_) return;
  int b = p / M_, i = p % M_;
  float ar = 0.f, ai = 0.f;
  for (int j = 0; j < 4; ++j) {
    int t = lane + 64 * j;
    float te = t_emb[b * T_ + t];
    ar += te * dwr[(size_t)i * T_ + t];
    ai += te * dwi[(size_t)i * T_ + t];
  }
  for (int off = 32; off > 0; off >>= 1) {
    ar += __shfl_down(ar, off, 64);
    ai += __shfl_down(ai, off, 64);
  }
  if (lane == 0) { tmr[b * M_ + i] = ar; tmi[b * M_ + i] = ai; }
}

// ------- Kernel T1: x (B,N,C) -> packed complex planes z (B*C, H) ------------
__global__ __launch_bounds__(256) void pack_transpose(
    const float* __restrict__ x, float* __restrict__ zre, float* __restrict__ zim) {
  __shared__ float tile[64][65];
  int b = blockIdx.y, nt = blockIdx.x;
  int n0 = nt * 64;
  int j  = threadIdx.x & 63;
  int iy = threadIdx.x >> 6;
  for (int p = 0; p < 16; ++p) {
    int i = iy + 4 * p;
    tile[i][j] = x[((size_t)(b * N_ + n0 + i)) * CIN + j];
  }
  __syncthreads();
  int ii = threadIdx.x & 31;
  int cy = threadIdx.x >> 5;
  int h0 = nt * 32;
  for (int p = 0; p < 8; ++p) {
    int c = cy + 8 * p;
    size_t o = (size_t)(b * CIN + c) * H_ + h0 + ii;
    zre[o] = tile[2 * ii][c];
    zim[o] = tile[2 * ii + 1][c];
  }
}

// ---------------- Kernel B: forward FFT (length H) + rfft split --------------
__global__ __launch_bounds__(512, 4) void fft_fwd(
    const float* __restrict__ zre, const float* __restrict__ zim,
    float* __restrict__ Xre, float* __restrict__ Xim) {
  __shared__ float sre[H_], sim[H_];
  int bc = blockIdx.x;
  int tid = threadIdx.x;
  size_t base = (size_t)bc * H_;
#pragma unroll
  for (int s = 0; s < 16; ++s) {
    int n = tid + 512 * s;
    int r = SW((int)br13(n));
    sre[r] = zre[base + n];
    sim[r] = zim[base + n];
  }
  __syncthreads();
  group16<-1, 0>(sre, sim, tid); __syncthreads();
  group16<-1, 4>(sre, sim, tid); __syncthreads();
  group16<-1, 8>(sre, sim, tid); __syncthreads();
  stageD<-1>(sre, sim, tid);     __syncthreads();
  const float sc = 1.0f / (float)N_;
  for (int k = tid; k < M_; k += 512) {
    int mk = (H_ - k) & (H_ - 1);
    int pk = SW(k), pm = SW(mk);
    float zr = sre[pk], zi = sim[pk];
    float mr = sre[pm], mi = -sim[pm];
    float Er = 0.5f * (zr + mr), Ei = 0.5f * (zi + mi);
    float Dr = zr - mr,          Di = zi - mi;
    float Or = 0.5f * Di,        Oi = -0.5f * Dr;
    float ang = -6.283185307179586f * (float)k / (float)N_;
    float sn, cs;
    __sincosf(ang, &sn, &cs);
    float Xr = Er + cs * Or - sn * Oi;
    float Xi = Ei + cs * Oi + sn * Or;
    Xre[(size_t)bc * M_ + k] = Xr * sc;
    Xim[(size_t)bc * M_ + k] = Xi * sc;
  }
}

// ---------------- Kernel C: per-frequency channel mix via MFMA (bf16x3) ------
// Y[i,b,o] = tmod[b,i] * sum_c X[i,b,c]*W[i,c,o]
// A-read: from X (bc, M) layout at stride M — scattered dwords. The 16
// consecutive i sharing each 64B line are grouped onto ONE XCD by the
// block-id swizzle below (R6 lesson: cross-XCD sharers refetch per-XCD L2,
// 5.7x amplification; same-XCD co-resident sharers dedup perfectly, R2).
// Y-write: coalesced (i, bo) rows — writes must stay line-coalesced (R5).
typedef short  s8v  __attribute__((ext_vector_type(8)));
typedef float  f4v  __attribute__((ext_vector_type(4)));

__device__ __forceinline__ unsigned short f2bf_hi(float x) {
  unsigned u = __float_as_uint(x);
  unsigned r = (u + 0x7fffu + ((u >> 16) & 1u)) >> 16;   // RNE
  return (unsigned short)r;
}

// B-fragment LDS index: slab = (n>>4)*2 + (k>>5); L = (n&15) + ((k>>3)&3)*16; j = k&7
__device__ __forceinline__ int fbi(int k, int n) {
  return ((((n >> 4) * 2 + (k >> 5)) << 9) | (((n & 15) + (((k >> 3) & 3) << 4)) << 3) | (k & 7));
}
// A-fragment LDS index: slab = k>>5
__device__ __forceinline__ int fai(int k, int m) {
  return (((k >> 5) << 9) | (((m & 15) + (((k >> 3) & 3) << 4)) << 3) | (k & 7));
}

__global__ __launch_bounds__(256) void mix_mfma(
    const float* __restrict__ Xre, const float* __restrict__ Xim,
    const float* __restrict__ Wr_g, const float* __restrict__ Wi_g,
    const float* __restrict__ tmr, const float* __restrict__ tmi,
    float* __restrict__ Yr_g, float* __restrict__ Yi_g) {
  __shared__ __align__(16) unsigned short BrH[4096], BrL[4096], BiH[4096], BiL[4096];
  __shared__ __align__(16) unsigned short ArH[1024], ArL[1024];
  __shared__ __align__(16) unsigned short AiH[1024], AiL[1024];
  __shared__ __align__(16) unsigned short AnH[1024], AnL[1024];  // -Ai
  __shared__ float tms[32];
  // XCD-grouping swizzle: ids d<2048 -> (q,j,p); group g=q*8+p gets the 16
  // line-sharing frequencies i=g*16+j on one XCD within a 128-id window.
  const int d = blockIdx.x;
  const int i = (d == 2048) ? 2048
              : ((d >> 7) * 8 + (d & 7)) * 16 + ((d >> 3) & 15);
  const int tid = threadIdx.x;

  // --- stage X -> bf16 hi/lo A-fragments (+negated imag); strided reads ---
  {
    int idx0 = tid * 4;
    float er[4], ei[4];
#pragma unroll
    for (int e = 0; e < 4; ++e) {
      int idx = idx0 + e;                       // bc = b*64 + c, 0..1023
      er[e] = Xre[(size_t)idx * M_ + i];
      ei[e] = Xim[(size_t)idx * M_ + i];
    }
#pragma unroll
    for (int e = 0; e < 4; ++e) {
      int idx = idx0 + e;
      int m = idx >> 6, k = idx & 63;
      int a = fai(k, m);
      unsigned short h = f2bf_hi(er[e]);
      float hf = __uint_as_float(((unsigned)h) << 16);
      ArH[a] = h; ArL[a] = f2bf_hi(er[e] - hf);
      h = f2bf_hi(ei[e]);
      unsigned short l = f2bf_hi(ei[e] - __uint_as_float(((unsigned)h) << 16));
      AiH[a] = h; AiL[a] = l;
      AnH[a] = h ^ 0x8000u; AnL[a] = l ^ 0x8000u;
    }
  }
  // --- stage W -> bf16 hi/lo fragments ---
  const float4* wr4 = (const float4*)(Wr_g + (size_t)i * 4096);
  const float4* wi4 = (const float4*)(Wi_g + (size_t)i * 4096);
#pragma unroll
  for (int it = 0; it < 4; ++it) {
    int f4 = it * 256 + tid;          // 0..1023
    float4 vr = wr4[f4];
    float4 vi = wi4[f4];
    int idx0 = f4 * 4;
    float er[4] = {vr.x, vr.y, vr.z, vr.w};
    float ei[4] = {vi.x, vi.y, vi.z, vi.w};
#pragma unroll
    for (int e = 0; e < 4; ++e) {
      int idx = idx0 + e;
      int k = idx >> 6, n = idx & 63;
      int a = fbi(k, n);
      unsigned short h = f2bf_hi(er[e]);
      float hf = __uint_as_float(((unsigned)h) << 16);
      BrH[a] = h; BrL[a] = f2bf_hi(er[e] - hf);
      h = f2bf_hi(ei[e]);
      hf = __uint_as_float(((unsigned)h) << 16);
      BiH[a] = h; BiL[a] = f2bf_hi(ei[e] - hf);
    }
  }
  if (tid < 16) {
    tms[tid]      = tmr[tid * M_ + i];
    tms[16 + tid] = tmi[tid * M_ + i];
  }
  __syncthreads();

  const int w = tid >> 6, L = tid & 63;
  const s8v* pArH = (const s8v*)ArH; const s8v* pArL = (const s8v*)ArL;
  const s8v* pAiH = (const s8v*)AiH; const s8v* pAiL = (const s8v*)AiL;
  const s8v* pAnH = (const s8v*)AnH; const s8v* pAnL = (const s8v*)AnL;
  const s8v* pBrH = (const s8v*)BrH; const s8v* pBrL = (const s8v*)BrL;
  const s8v* pBiH = (const s8v*)BiH; const s8v* pBiL = (const s8v*)BiL;

  f4v cr = {0.f, 0.f, 0.f, 0.f}, ci = {0.f, 0.f, 0.f, 0.f};
#pragma unroll
  for (int s = 0; s < 2; ++s) {
    s8v arh = pArH[s * 64 + L], arl = pArL[s * 64 + L];
    s8v aih = pAiH[s * 64 + L], ail = pAiL[s * 64 + L];
    s8v anh = pAnH[s * 64 + L], anl = pAnL[s * 64 + L];
    int bo = (w * 2 + s) * 64 + L;
    s8v brh = pBrH[bo], brl = pBrL[bo];
    s8v bih = pBiH[bo], bil = pBiL[bo];
    cr = __builtin_amdgcn_mfma_f32_16x16x32_bf16(arh, brh, cr, 0, 0, 0);
    cr = __builtin_amdgcn_mfma_f32_16x16x32_bf16(arh, brl, cr, 0, 0, 0);
    cr = __builtin_amdgcn_mfma_f32_16x16x32_bf16(arl, brh, cr, 0, 0, 0);
    cr = __builtin_amdgcn_mfma_f32_16x16x32_bf16(anh, bih, cr, 0, 0, 0);
    cr = __builtin_amdgcn_mfma_f32_16x16x32_bf16(anh, bil, cr, 0, 0, 0);
    cr = __builtin_amdgcn_mfma_f32_16x16x32_bf16(anl, bih, cr, 0, 0, 0);
    ci = __builtin_amdgcn_mfma_f32_16x16x32_bf16(arh, bih, ci, 0, 0, 0);
    ci = __builtin_amdgcn_mfma_f32_16x16x32_bf16(arh, bil, ci, 0, 0, 0);
    ci = __builtin_amdgcn_mfma_f32_16x16x32_bf16(arl, bih, ci, 0, 0, 0);
    ci = __builtin_amdgcn_mfma_f32_16x16x32_bf16(aih, brh, ci, 0, 0, 0);
    ci = __builtin_amdgcn_mfma_f32_16x16x32_bf16(aih, brl, ci, 0, 0, 0);
    ci = __builtin_amdgcn_mfma_f32_16x16x32_bf16(ail, brh, ci, 0, 0, 0);
  }

  const int n = (L & 15) + 16 * w;
  const int quad = L >> 4;
#pragma unroll
  for (int r = 0; r < 4; ++r) {
    int m = quad * 4 + r;
    float tr = tms[m], ti = tms[16 + m];
    float yr = tr * cr[r] - ti * ci[r];
    float yi = tr * ci[r] + ti * cr[r];
    size_t o = (size_t)i * 1024 + m * 64 + n;
    Yr_g[o] = yr;
    Yi_g[o] = yi;
  }
}

// ---------------- Kernel D: inverse packing + inverse FFT --------------------
// Reads Y in (k, bo) layout — scattered dwords at stride 4KB. The 16 bo
// sharing each 64B line are grouped onto one XCD by the id swizzle.
// Writes z planes coalesced.
__global__ __launch_bounds__(512, 4) void fft_inv(
    const float* __restrict__ Ytr, const float* __restrict__ Yti,
    float* __restrict__ zre, float* __restrict__ zim) {
  __shared__ float sre[H_], sim[H_];
  // XCD-grouping swizzle: 1024 ids -> 64 groups of 16 line-sharing bo.
  const int d = blockIdx.x;
  const int bo = ((d >> 7) * 8 + (d & 7)) * 16 + ((d >> 3) & 15);
  int tid = threadIdx.x;
#pragma unroll
  for (int s = 0; s < 16; ++s) {
    int k = tid + 512 * s;
    float ykr = 0.f, yki = 0.f, ymr = 0.f, ymi = 0.f;
    if (k < M_) {
      ykr = Ytr[(size_t)k * 1024 + bo];
      yki = Yti[(size_t)k * 1024 + bo];
    }
    int m = H_ - k;
    if (m < M_) {
      ymr = Ytr[(size_t)m * 1024 + bo];
      ymi = -Yti[(size_t)m * 1024 + bo];
    }
    float Sr = ykr + ymr, Si = yki + ymi;
    float Dr = ykr - ymr, Di = yki - ymi;
    float ang = 6.283185307179586f * (float)k / (float)N_;
    float sn, cs;
    __sincosf(ang, &sn, &cs);
    float Zr = Sr - (cs * Di + sn * Dr);
    float Zi = Si + (cs * Dr - sn * Di);
    int r = SW((int)br13(k));
    sre[r] = Zr; sim[r] = Zi;
  }
  __syncthreads();
  group16<1, 0>(sre, sim, tid); __syncthreads();
  group16<1, 4>(sre, sim, tid); __syncthreads();
  group16<1, 8>(sre, sim, tid); __syncthreads();
  stageD<1>(sre, sim, tid);     __syncthreads();
  size_t base = (size_t)bo * H_;
#pragma unroll
  for (int s = 0; s < 16; ++s) {
    int n = tid + 512 * s;
    int p = SW(n);
    zre[base + n] = sre[p];
    zim[base + n] = sim[p];
  }
}

// ------- Kernel T4: z planes (B*Cout, H) -> out (B, N, Cout) -----------------
__global__ __launch_bounds__(256) void unpack_transpose(
    const float* __restrict__ zre, const float* __restrict__ zim,
    float* __restrict__ out) {
  __shared__ float tre[64][33], tim[64][33];
  int b = blockIdx.y, ht = blockIdx.x;
  int h0 = ht * 32;
  int ii = threadIdx.x & 31, cy = threadIdx.x >> 5;
  for (int p = 0; p < 8; ++p) {
    int c = cy + 8 * p;
    size_t idx = (size_t)(b * COUT + c) * H_ + h0 + ii;
    tre[c][ii] = zre[idx];
    tim[c][ii] = zim[idx];
  }
  __syncthreads();
  int o = threadIdx.x & 63, ry = threadIdx.x >> 6;
  for (int p = 0; p < 16; ++p) {
    int r = ry + 4 * p;
    int n = h0 * 2 + r;
    float v = (r & 1) ? tim[o][r >> 1] : tre[o][r >> 1];
    out[((size_t)(b * N_ + n)) * COUT + o] = v;
  }
}

extern "C" void kernel_launch(void* const* d_in, const int* in_sizes, int n_in,
                              void* d_out, int out_size, void* d_ws, size_t ws_size,
                              hipStream_t stream) {
  const float* x    = (const float*)d_in[0];
  const float* temb = (const float*)d_in[1];
  const float* wr   = (const float*)d_in[2];
  const float* wi   = (const float*)d_in[3];
  const float* dwr  = (const float*)d_in[4];
  const float* dwi  = (const float*)d_in[5];
  float* out = (float*)d_out;

  float* ws  = (float*)d_ws;
  float* tmr = ws;
  float* tmi = tmr + 32784;
  float* zre = tmi + 32784;                // (B*C, H) — reused by inverse
  float* zim = zre + 8388608;
  float* Xre = zim + 8388608;              // X (bc, k)
  float* Xim = Xre + 2098176;
  float* Yre = Xim + 2098176;              // Y (k, bo)
  float* Yim = Yre + 2098176;

  tmod_kernel<<<dim3((B_ * M_ + 3) / 4), 256, 0, stream>>>(temb, dwr, dwi, tmr, tmi);
  pack_transpose<<<dim3(N_ / 64, B_), 256, 0, stream>>>(x, zre, zim);
  fft_fwd<<<dim3(B_ * CIN), 512, 0, stream>>>(zre, zim, Xre, Xim);
  mix_mfma<<<dim3(M_), 256, 0, stream>>>(Xre, Xim, wr, wi, tmr, tmi, Yre, Yim);
  fft_inv<<<dim3(B_ * COUT), 512, 0, stream>>>(Yre, Yim, zre, zim);
  unpack_transpose<<<dim3(H_ / 32, B_), 256, 0, stream>>>(zre, zim, out);
}